// Round 16
// baseline (612.549 us; speedup 1.0000x reference)
//
#include <hip/hip_runtime.h>
#include <math.h>

// MoE: B=2 S=2048 D=1024 E=8 H=4096 K=2
#define Bc 2
#define Sc 2048
#define Dc 1024
#define Ec 8
#define Hc 4096
#define Tc (Bc*Sc)          // 4096 tokens
#define NSLOT (Tc*2)        // 8192 token-expert slots (top-2 always)
#define SLOTPAD 8448        // NSLOT + 256 slack rows (padded tile over-read)
#define FINAL_N ((size_t)Tc*Dc)
#define PROWS ((size_t)SLOTPAD*32)   // ushorts per 32-wide K-panel of A/HH

typedef float f32x4 __attribute__((ext_vector_type(4)));
typedef __bf16 bf16x8 __attribute__((ext_vector_type(8)));

__device__ __forceinline__ unsigned short f2bf(float f) {
    union { float f; unsigned int u; } v; v.f = f;
    return (unsigned short)((v.u + 0x7fffu + ((v.u >> 16) & 1u)) >> 16);
}
__device__ __forceinline__ unsigned int pack2bf(float a, float b) {
    return (unsigned int)f2bf(a) | ((unsigned int)f2bf(b) << 16);
}

// async global->LDS, 16B per lane; contiguous 1KB per instruction (panel-major sources)
__device__ __forceinline__ void gload16(const unsigned short* g, unsigned short* l) {
    __builtin_amdgcn_global_load_lds(
        (const __attribute__((address_space(1))) unsigned int*)g,
        (__attribute__((address_space(3))) unsigned int*)l,
        16, 0, 0);
}

// raw barrier with compiler fences (NO vmcnt(0) drain, unlike __syncthreads)
__device__ __forceinline__ void fence_bar() {
    __builtin_amdgcn_sched_barrier(0);
    asm volatile("s_barrier" ::: "memory");
    __builtin_amdgcn_sched_barrier(0);
}

// ------- [R][C] fp32 -> panel-major bf16 [C/128][R/32][128][32], chunk-XOR pre-swizzled -------
__global__ void k_transpose_panel(const float* __restrict__ inA, const float* __restrict__ inB,
                                  unsigned short* __restrict__ outA, unsigned short* __restrict__ outB,
                                  int R, int C, int nz_per_mat) {
    __shared__ float tile[64][65];
    int z = blockIdx.z;
    const float* in; unsigned short* out;
    if (z < nz_per_mat) { in = inA; out = outA; }
    else { in = inB; out = outB; z -= nz_per_mat; }
    size_t zbase = (size_t)z * (size_t)R * C;
    int R32 = R >> 5;
    int cb = blockIdx.x * 64, rb = blockIdx.y * 64;
    int t = threadIdx.x;             // 256
    int q = t & 15, g = t >> 4;
    #pragma unroll
    for (int j = 0; j < 4; j++) {
        int row = g + 16*j;
        float4 v = *(const float4*)&in[zbase + (size_t)(rb+row)*C + cb + q*4];
        tile[row][q*4+0] = v.x; tile[row][q*4+1] = v.y;
        tile[row][q*4+2] = v.z; tile[row][q*4+3] = v.w;
    }
    __syncthreads();
    #pragma unroll
    for (int j = 0; j < 4; j++) {
        int co = g + 16*j;
        int c = cb + co;
        int r0 = rb + q*4;
        ushort4 o;
        o.x = f2bf(tile[q*4+0][co]); o.y = f2bf(tile[q*4+1][co]);
        o.z = f2bf(tile[q*4+2][co]); o.w = f2bf(tile[q*4+3][co]);
        int cr = c & 127;
        int ch = ((r0 >> 3) & 3) ^ ((cr >> 1) & 3);
        size_t off = zbase + (((size_t)(c >> 7) * R32 + (r0 >> 5)) * 4096)
                   + (size_t)cr * 32 + ch * 8 + (r0 & 7);
        *(ushort4*)&out[off] = o;
    }
}

// ---------------- gating: one wave per token ----------------
__global__ void k_gate(const float* __restrict__ x, const float* __restrict__ noise,
                       const float* __restrict__ Wg, const float* __restrict__ nw,
                       float* __restrict__ out_idx, int* __restrict__ counts,
                       int* __restrict__ tok_top, float* __restrict__ tok_w) {
    int t = blockIdx.x;
    int lane = threadIdx.x;                     // 64
    const float* xr = x + (size_t)t * Dc;
    double acc[Ec];
    #pragma unroll
    for (int e = 0; e < Ec; e++) acc[e] = 0.0;
    for (int i = 0; i < Dc/64; i++) {
        int d = lane + i*64;
        double xv = (double)xr[d];
        #pragma unroll
        for (int e = 0; e < Ec; e++) acc[e] += xv * (double)Wg[e*Dc + d];
    }
    #pragma unroll
    for (int e = 0; e < Ec; e++)
        for (int off = 32; off > 0; off >>= 1)
            acc[e] += __shfl_down(acc[e], off);
    if (lane == 0) {
        double noisy[Ec];
        #pragma unroll
        for (int e = 0; e < Ec; e++)
            noisy[e] = acc[e] + (double)noise[t*Ec + e] * (double)nw[e];
        int i0 = 0;
        for (int e = 1; e < Ec; e++) if (noisy[e] > noisy[i0]) i0 = e;   // ties -> lowest idx
        int i1 = -1;
        for (int e = 0; e < Ec; e++) {
            if (e == i0) continue;
            if (i1 < 0 || noisy[e] > noisy[i1]) i1 = e;
        }
        double ee = exp(noisy[i1] - noisy[i0]);   // v1 <= v0, stable
        float w0 = (float)(1.0 / (1.0 + ee));
        float w1 = (float)(ee / (1.0 + ee));
        out_idx[t*2 + 0] = (float)i0;
        out_idx[t*2 + 1] = (float)i1;
        tok_top[t*2] = i0; tok_top[t*2+1] = i1;
        tok_w[t*2] = w0;   tok_w[t*2+1] = w1;
        atomicAdd(&counts[i0], 1);
        atomicAdd(&counts[i1], 1);
    }
}

__global__ void k_scan(const int* __restrict__ counts, int* __restrict__ offsets) {
    if (threadIdx.x == 0) {
        int s = 0;
        for (int e = 0; e < Ec; e++) { offsets[e] = s; s += counts[e]; }
        offsets[Ec] = s;
    }
}

__global__ void k_fill(const int* __restrict__ tok_top, const int* __restrict__ offsets,
                       int* __restrict__ fill, int* __restrict__ slot_token,
                       int* __restrict__ slot_of, int* __restrict__ slot_pos) {
    int t = blockIdx.x * 256 + threadIdx.x;
    if (t >= Tc) return;
    #pragma unroll
    for (int j = 0; j < 2; j++) {
        int e = tok_top[t*2 + j];
        int pos = atomicAdd(&fill[e], 1);
        int slot = offsets[e] + pos;
        slot_token[slot] = t;
        slot_of[t*2 + j] = slot;
        slot_pos[slot] = pos;                 // expert-local row (swizzle key source)
    }
}

// ---- pack A: gather + cvt into K-panel-major APK[kp=32][SLOTPAD][32], pre-swizzled ----
__global__ void k_packA(const float* __restrict__ x, const int* __restrict__ slot_token,
                        const int* __restrict__ slot_pos, unsigned short* __restrict__ apk) {
    int s = blockIdx.x * 4 + (threadIdx.x >> 6);
    int lane = threadIdx.x & 63;
    int token = slot_token[s];
    int pos = slot_pos[s];
    const float4* px = (const float4*)(x + (size_t)token * Dc) + lane*4;
    float4 v0 = px[0], v1 = px[1], v2 = px[2], v3 = px[3];
    uint4 lo, hi;
    lo.x = pack2bf(v0.x, v0.y); lo.y = pack2bf(v0.z, v0.w);
    lo.z = pack2bf(v1.x, v1.y); lo.w = pack2bf(v1.z, v1.w);
    hi.x = pack2bf(v2.x, v2.y); hi.y = pack2bf(v2.z, v2.w);
    hi.z = pack2bf(v3.x, v3.y); hi.w = pack2bf(v3.z, v3.w);
    int kp = lane >> 1;
    int key = (pos >> 1) & 3;
    int c0 = (lane & 1) * 2;
    size_t base = (size_t)kp * PROWS + (size_t)s * 32;
    *(uint4*)&apk[base + ((c0 ^ key) * 8)]       = lo;
    *(uint4*)&apk[base + (((c0+1) ^ key) * 8)]   = hi;
}

// ---------------- GEMM1: HH = (X@W1+b1) * silu(X@W2+b2), per expert ----------------
// Best-measured cell (R9/R11/R15, UNCHANGED): default 3D grid (bx fastest -> 64
// consecutive blocks share one A-tile), 128 slots x 64 hcols x both matrices; 4 waves,
// single 64x64 acc/wave; 2-slot ring + counted vmcnt + raw barriers; 32KB LDS; 4 blocks/CU.
__global__ __launch_bounds__(256, 4) void k_gemm1(
    const unsigned short* __restrict__ apk,
    const unsigned short* __restrict__ w1p, const unsigned short* __restrict__ w2p,
    const float* __restrict__ b1, const float* __restrict__ b2,
    const int* __restrict__ counts, const int* __restrict__ offsets,
    unsigned short* __restrict__ hh2) {
    int e = blockIdx.z;
    int n_e = counts[e];
    int m0 = blockIdx.y * 128;
    if (m0 >= n_e) return;
    int base = offsets[e];
    int bx = blockIdx.x;                 // 64 x-blocks of 64 h-cols
    int n0 = bx * 64;
    int hp = bx >> 1, ro = (bx & 1) * 64;   // 128-panel + row offset inside it

    __shared__ __align__(16) unsigned char smem[32768];
    unsigned short* sU = (unsigned short*)smem;   // A slot s: +s*4096, B slot s: +8192+s*4096
    float* sS = (float*)smem;                     // [128][64] epilogue silu exchange (aliases)

    int tid = threadIdx.x;
    int wid = tid >> 6, lane = tid & 63;
    int wr = wid >> 1, wc = wid & 1;

    // contiguous staging sources
    const unsigned short* aSrc = apk + (size_t)(base + m0 + wid*32)*32 + lane*8;   // + kk*PROWS
    const unsigned short* wmat = (wid < 2) ? w1p : w2p;
    const unsigned short* bSrc = wmat + ((size_t)(e*32 + hp) * 32) * 4096
                               + (size_t)(ro + (wid & 1)*32)*32 + lane*8;          // + kk*4096

    int arow = lane & 15, cr = lane >> 4;
    int ccf = cr ^ ((arow >> 1) & 3);
    int aoff[4], boff[4];
    #pragma unroll
    for (int m = 0; m < 4; m++) aoff[m] = (wr*64 + m*16 + arow)*32 + ccf*8;
    #pragma unroll
    for (int n = 0; n < 4; n++) boff[n] = 8192 + (wc*64 + n*16 + arow)*32 + ccf*8;

    f32x4 acc[4][4];
    #pragma unroll
    for (int m = 0; m < 4; m++)
        #pragma unroll
        for (int n = 0; n < 4; n++)
            #pragma unroll
            for (int j = 0; j < 4; j++) acc[m][n][j] = 0.0f;

    // rolling stage pointers (no per-step 64-bit multiplies)
    const unsigned short* aStage = aSrc;
    const unsigned short* bStage = bSrc;

    auto STAGE = [&](int s) {   // stages the tile currently pointed at; 4 contiguous 1KB loads
        unsigned short* dA = sU + s*4096 + wid*1024;
        unsigned short* dB = sU + 8192 + s*4096 + wid*1024;
        gload16(aStage,       dA); gload16(aStage + 512, dA + 512);
        gload16(bStage,       dB); gload16(bStage + 512, dB + 512);
        aStage += PROWS; bStage += 4096;
    };

    const int NK = Dc / 32;   // 32
    STAGE(0); STAGE(1);
    for (int kk = 0; kk < NK; ++kk) {
        int s = kk & 1;
        const unsigned short* sl = sU + s*4096;
        if (kk < NK - 1) { asm volatile("s_waitcnt vmcnt(4)" ::: "memory"); }
        else             { asm volatile("s_waitcnt vmcnt(0)" ::: "memory"); }
        fence_bar();                          // slot s published to all waves
        bf16x8 af[4], bf[4];
        #pragma unroll
        for (int m = 0; m < 4; m++) af[m] = *(const bf16x8*)&sl[aoff[m]];
        #pragma unroll
        for (int n = 0; n < 4; n++) bf[n] = *(const bf16x8*)&sl[boff[n]];
        #pragma unroll
        for (int m = 0; m < 4; m++)
            #pragma unroll
            for (int n = 0; n < 4; n++)
                acc[m][n] = __builtin_amdgcn_mfma_f32_16x16x32_bf16(af[m], bf[n], acc[m][n], 0, 0, 0);
        fence_bar();                          // all waves done reading slot s (WAR license)
        if (kk + 2 < NK) STAGE(s);            // refill slot s; waited at iter kk+2
    }

    // epilogue: wc=1 publish silu(h2) to LDS; wc=0 multiply+store.
    // row-parity XOR on the column (function of row only, same on write and read).
    int lrow = (lane >> 4) * 4, lcol = lane & 15;
    if (wc == 1) {
        #pragma unroll
        for (int n = 0; n < 4; n++) {
            float b2v = b2[e*Hc + n0 + n*16 + lcol];
            #pragma unroll
            for (int m = 0; m < 4; m++) {
                int rb = wr*64 + m*16 + lrow;
                #pragma unroll
                for (int j = 0; j < 4; j++) {
                    int row = rb + j;
                    float h2 = acc[m][n][j] + b2v;
                    sS[row*64 + ((n*16 + lcol) ^ ((((row) >> 2) & 1) << 4))] = h2 / (1.0f + expf(-h2));
                }
            }
        }
    }
    __syncthreads();
    if (wc == 0) {
        #pragma unroll
        for (int n = 0; n < 4; n++) {
            int hcol = n0 + n*16 + lcol;
            float b1v = b1[e*Hc + hcol];
            int hp2 = hcol >> 5;
            int ch  = (hcol >> 3) & 3;
            int ho  = hcol & 7;
            #pragma unroll
            for (int m = 0; m < 4; m++) {
                int rb = wr*64 + m*16 + lrow;
                #pragma unroll
                for (int j = 0; j < 4; j++) {
                    int row = rb + j;
                    int r = m0 + row;
                    if (r < n_e) {
                        float sv = sS[row*64 + ((n*16 + lcol) ^ ((((row) >> 2) & 1) << 4))];
                        float v = (acc[m][n][j] + b1v) * sv;
                        int key = (r >> 1) & 3;
                        hh2[(size_t)hp2 * PROWS + (size_t)(base + r)*32 + ((ch ^ key)*8) + ho] = f2bf(v);
                    }
                }
            }
        }
    }
}

// ---------------- GEMM2: OUT = HH @ Wp^T (+bp), per expert, K-split x2 ----------------
// UNBUNDLING R10->R11: keep R11's XCD swizzle (expert per XCD, dp fastest = A-tile
// shared by 8 consecutive blocks), but revert the ring to 2-slot / 32KB / vmcnt(4)
// at 4 blocks/CU: per XCD there are exactly 128 active blocks over 32 CUs = 4/CU,
// so residency 4/CU runs as ONE wave (the 3-slot/48KB version ran 1.33 waves with a
// 1-block/CU tail). Swizzled L2-hot staging makes the shallower prefetch sufficient.
// Partials in disjoint OUTB halves via plain stores; kc=0 adds bias.
__global__ __launch_bounds__(256, 4) void k_gemm2(
    const unsigned short* __restrict__ hh2,
    const unsigned short* __restrict__ wpp,
    const float* __restrict__ bp,
    const int* __restrict__ counts, const int* __restrict__ offsets,
    float* __restrict__ outb) {
    int d = blockIdx.x;                          // 0..4095 dispatch index
    int L = (d & 7) * 512 + (d >> 3);            // bijective; XCD i owns L in [i*512,(i+1)*512)
    int dp = L & 7;                              // FASTEST (A-tile shared by 8 consecutive blocks)
    int yy = (L >> 3) & 63;
    int e  = L >> 9;                             // expert per XCD
    int n_e = counts[e];
    int kc = yy & 1;                             // K-chunk
    int m0 = (yy >> 1) * 128;
    if (m0 >= n_e) return;
    int base = offsets[e];
    int n0 = dp * 128;
    float* out = outb + (size_t)kc * NSLOT * Dc; // disjoint partial half

    __shared__ __align__(16) unsigned char smem[32768];
    unsigned short* sU = (unsigned short*)smem;  // A slot s: +s*4096, B slot s: +8192+s*4096

    int tid = threadIdx.x;
    int wid = tid >> 6, lane = tid & 63;
    int wr = wid >> 1, wc = wid & 1;

    const int k0 = kc * 64;                      // first 32-wide K-panel of this chunk
    const unsigned short* aSrc = hh2 + (size_t)k0*PROWS
                               + (size_t)(base + m0 + wid*32)*32 + lane*8;           // + kk*PROWS
    const unsigned short* bSrc = wpp + ((size_t)(e*8 + dp) * 128) * 4096
                               + (size_t)k0*4096 + wid*1024 + lane*8;                // + kk*4096

    int arow = lane & 15, cr = lane >> 4;
    int ccf = cr ^ ((arow >> 1) & 3);
    int aoff[4], boff[4];
    #pragma unroll
    for (int m = 0; m < 4; m++) aoff[m] = (wr*64 + m*16 + arow)*32 + ccf*8;
    #pragma unroll
    for (int n = 0; n < 4; n++) boff[n] = 8192 + (wc*64 + n*16 + arow)*32 + ccf*8;

    f32x4 acc[4][4];
    #pragma unroll
    for (int m = 0; m < 4; m++)
        #pragma unroll
        for (int n = 0; n < 4; n++)
            #pragma unroll
            for (int j = 0; j < 4; j++) acc[m][n][j] = 0.0f;

    const unsigned short* aStage = aSrc;
    const unsigned short* bStage = bSrc;
    auto STAGE = [&](int s) {
        unsigned short* dA = sU + s*4096 + wid*1024;
        unsigned short* dB = sU + 8192 + s*4096 + wid*1024;
        gload16(aStage,       dA); gload16(aStage + 512, dA + 512);
        gload16(bStage,       dB); gload16(bStage + 512, dB + 512);
        aStage += PROWS; bStage += 4096;
    };

    const int NK = 64;                   // 2048 K per chunk / 32
    STAGE(0); STAGE(1);
    for (int kk = 0; kk < NK; ++kk) {
        int s = kk & 1;
        const unsigned short* sl = sU + s*4096;
        if (kk < NK - 1) { asm volatile("s_waitcnt vmcnt(4)" ::: "memory"); }
        else             { asm volatile("s_waitcnt vmcnt(0)" ::: "memory"); }
        fence_bar();                          // slot s published to all waves
        bf16x8 af[4], bf[4];
        #pragma unroll
        for (int m = 0; m < 4; m++) af[m] = *(const bf16x8*)&sl[aoff[m]];
        #pragma unroll
        for (int n = 0; n < 4; n++) bf[n] = *(const bf16x8*)&sl[boff[n]];
        #pragma unroll
        for (int m = 0; m < 4; m++)
            #pragma unroll
            for (int n = 0; n < 4; n++)
                acc[m][n] = __builtin_amdgcn_mfma_f32_16x16x32_bf16(af[m], bf[n], acc[m][n], 0, 0, 0);
        fence_bar();                          // WAR license on slot s
        if (kk + 2 < NK) STAGE(s);            // refill slot s; waited at iter kk+2
    }

    int lrow = (lane >> 4) * 4, lcol = lane & 15;
    #pragma unroll
    for (int n = 0; n < 4; n++) {
        int dcol = n0 + wc*64 + n*16 + lcol;
        float badd = (kc == 0) ? bp[e*Dc + dcol] : 0.0f;
        #pragma unroll
        for (int m = 0; m < 4; m++) {
            int rb2 = m0 + wr*64 + m*16 + lrow;
            #pragma unroll
            for (int j = 0; j < 4; j++) {
                int r = rb2 + j;
                if (r < n_e)
                    out[(size_t)(base + r)*Dc + dcol] = acc[m][n][j] + badd;
            }
        }
    }
}

// ---------------- combine: final[t] = w0*(P0+P1)[s0] + w1*(P0+P1)[s1] ----------------
__global__ void k_combine(const float* __restrict__ outb, const int* __restrict__ slot_of,
                          const float* __restrict__ tok_w, float* __restrict__ final_out) {
    int gid = blockIdx.x * 256 + threadIdx.x;   // Tc*Dc/4 threads
    int t = gid >> 8;
    int c = (gid & 255) * 4;
    int s0 = slot_of[t*2], s1 = slot_of[t*2 + 1];
    float w0 = tok_w[t*2], w1 = tok_w[t*2 + 1];
    const float* p1 = outb + (size_t)NSLOT * Dc;
    float4 a0 = *(const float4*)&outb[(size_t)s0*Dc + c];
    float4 b0 = *(const float4*)&p1  [(size_t)s0*Dc + c];
    float4 a1 = *(const float4*)&outb[(size_t)s1*Dc + c];
    float4 b1v = *(const float4*)&p1 [(size_t)s1*Dc + c];
    float4 r;
    r.x = w0*(a0.x + b0.x) + w1*(a1.x + b1v.x);
    r.y = w0*(a0.y + b0.y) + w1*(a1.y + b1v.y);
    r.z = w0*(a0.z + b0.z) + w1*(a1.z + b1v.z);
    r.w = w0*(a0.w + b0.w) + w1*(a1.w + b1v.w);
    *(float4*)&final_out[(size_t)t*Dc + c] = r;
}

extern "C" void kernel_launch(void* const* d_in, const int* in_sizes, int n_in,
                              void* d_out, int out_size, void* d_ws, size_t ws_size,
                              hipStream_t stream) {
    (void)in_sizes; (void)n_in; (void)out_size; (void)ws_size;
    const float* x     = (const float*)d_in[0];
    const float* noise = (const float*)d_in[1];
    const float* Wg    = (const float*)d_in[2];
    const float* nw    = (const float*)d_in[3];
    const float* W1    = (const float*)d_in[4];
    const float* b1    = (const float*)d_in[5];
    const float* W2    = (const float*)d_in[6];
    const float* b2    = (const float*)d_in[7];
    const float* Wp    = (const float*)d_in[8];
    const float* bp    = (const float*)d_in[9];

    char* ws = (char*)d_ws;
    size_t off = 0;
    unsigned short* W1P = (unsigned short*)(ws + off); off += (size_t)Ec*Dc*Hc*2;      // 64 MB
    unsigned short* W2P = (unsigned short*)(ws + off); off += (size_t)Ec*Dc*Hc*2;      // 64 MB
    unsigned short* WPP = (unsigned short*)(ws + off); off += (size_t)Ec*Hc*Dc*2;      // 64 MB
    unsigned short* APK = (unsigned short*)(ws + off); off += (size_t)32*PROWS*2;      // 16.5 MB
    unsigned short* HH2 = (unsigned short*)(ws + off); off += (size_t)128*PROWS*2;     // 66 MB
    float*          OUTB= (float*)(ws + off);          off += (size_t)NSLOT*Dc*4*2;    // 64 MB (2 partials)
    int*   counts    = (int*)(ws + off);
    int*   fill      = (int*)(ws + off + 32);
    int*   offsets   = (int*)(ws + off + 64);
    int*   tok_top   = (int*)(ws + off + 128);
    float* tok_w     = (float*)(ws + off + 128 + (size_t)Tc*2*4);
    int*   slot_token= (int*)(ws + off + 128 + (size_t)Tc*2*8);
    int*   slot_of   = (int*)(ws + off + 128 + (size_t)Tc*2*8 + (size_t)NSLOT*4);
    int*   slot_pos  = (int*)(ws + off + 128 + (size_t)Tc*2*8 + (size_t)NSLOT*8);

    float* final_out = (float*)d_out;
    float* idx_out   = (float*)d_out + FINAL_N;

    (void)hipMemsetAsync(counts, 0, 64, stream);   // counts + fill

    // W1 + W2 panel transposes in one launch (z = 16: [0,8) -> W1, [8,16) -> W2)
    k_transpose_panel<<<dim3(Hc/64, Dc/64, 2*Ec), 256, 0, stream>>>(W1, W2, W1P, W2P, Dc, Hc, Ec);
    k_transpose_panel<<<dim3(Dc/64, Hc/64, Ec), 256, 0, stream>>>(Wp, Wp, WPP, WPP, Hc, Dc, Ec);

    k_gate<<<Tc, 64, 0, stream>>>(x, noise, Wg, nw, idx_out, counts, tok_top, tok_w);
    k_scan<<<1, 64, 0, stream>>>(counts, offsets);
    k_fill<<<Tc/256, 256, 0, stream>>>(tok_top, offsets, fill, slot_token, slot_of, slot_pos);
    k_packA<<<NSLOT/4, 256, 0, stream>>>(x, slot_token, slot_pos, APK);

    k_gemm1<<<dim3(Hc/64, Tc/128, Ec), 256, 0, stream>>>(APK, W1P, W2P, b1, b2,
                                                         counts, offsets, HH2);
    k_gemm2<<<4096, 256, 0, stream>>>(HH2, WPP, bp, counts, offsets, OUTB);
    k_combine<<<(Tc*Dc/4)/256, 256, 0, stream>>>(OUTB, slot_of, tok_w, final_out);
}

// Round 17
// 605.276 us; speedup vs baseline: 1.0120x; 1.0120x over previous
//
#include <hip/hip_runtime.h>
#include <math.h>

// MoE: B=2 S=2048 D=1024 E=8 H=4096 K=2
#define Bc 2
#define Sc 2048
#define Dc 1024
#define Ec 8
#define Hc 4096
#define Tc (Bc*Sc)          // 4096 tokens
#define NSLOT (Tc*2)        // 8192 token-expert slots (top-2 always)
#define SLOTPAD 8448        // NSLOT + 256 slack rows (padded tile over-read)
#define FINAL_N ((size_t)Tc*Dc)
#define PROWS ((size_t)SLOTPAD*32)   // ushorts per 32-wide K-panel of A/HH

typedef float f32x4 __attribute__((ext_vector_type(4)));
typedef __bf16 bf16x8 __attribute__((ext_vector_type(8)));

__device__ __forceinline__ unsigned short f2bf(float f) {
    union { float f; unsigned int u; } v; v.f = f;
    return (unsigned short)((v.u + 0x7fffu + ((v.u >> 16) & 1u)) >> 16);
}
__device__ __forceinline__ unsigned int pack2bf(float a, float b) {
    return (unsigned int)f2bf(a) | ((unsigned int)f2bf(b) << 16);
}

// async global->LDS, 16B per lane; contiguous 1KB per instruction (panel-major sources)
__device__ __forceinline__ void gload16(const unsigned short* g, unsigned short* l) {
    __builtin_amdgcn_global_load_lds(
        (const __attribute__((address_space(1))) unsigned int*)g,
        (__attribute__((address_space(3))) unsigned int*)l,
        16, 0, 0);
}

// raw barrier with compiler fences (NO vmcnt(0) drain, unlike __syncthreads)
__device__ __forceinline__ void fence_bar() {
    __builtin_amdgcn_sched_barrier(0);
    asm volatile("s_barrier" ::: "memory");
    __builtin_amdgcn_sched_barrier(0);
}

// ------- [R][C] fp32 -> panel-major bf16 [C/128][R/32][128][32], chunk-XOR pre-swizzled -------
__global__ void k_transpose_panel(const float* __restrict__ inA, const float* __restrict__ inB,
                                  unsigned short* __restrict__ outA, unsigned short* __restrict__ outB,
                                  int R, int C, int nz_per_mat) {
    __shared__ float tile[64][65];
    int z = blockIdx.z;
    const float* in; unsigned short* out;
    if (z < nz_per_mat) { in = inA; out = outA; }
    else { in = inB; out = outB; z -= nz_per_mat; }
    size_t zbase = (size_t)z * (size_t)R * C;
    int R32 = R >> 5;
    int cb = blockIdx.x * 64, rb = blockIdx.y * 64;
    int t = threadIdx.x;             // 256
    int q = t & 15, g = t >> 4;
    #pragma unroll
    for (int j = 0; j < 4; j++) {
        int row = g + 16*j;
        float4 v = *(const float4*)&in[zbase + (size_t)(rb+row)*C + cb + q*4];
        tile[row][q*4+0] = v.x; tile[row][q*4+1] = v.y;
        tile[row][q*4+2] = v.z; tile[row][q*4+3] = v.w;
    }
    __syncthreads();
    #pragma unroll
    for (int j = 0; j < 4; j++) {
        int co = g + 16*j;
        int c = cb + co;
        int r0 = rb + q*4;
        ushort4 o;
        o.x = f2bf(tile[q*4+0][co]); o.y = f2bf(tile[q*4+1][co]);
        o.z = f2bf(tile[q*4+2][co]); o.w = f2bf(tile[q*4+3][co]);
        int cr = c & 127;
        int ch = ((r0 >> 3) & 3) ^ ((cr >> 1) & 3);
        size_t off = zbase + (((size_t)(c >> 7) * R32 + (r0 >> 5)) * 4096)
                   + (size_t)cr * 32 + ch * 8 + (r0 & 7);
        *(ushort4*)&out[off] = o;
    }
}

// ---------------- gating: one wave per token ----------------
__global__ void k_gate(const float* __restrict__ x, const float* __restrict__ noise,
                       const float* __restrict__ Wg, const float* __restrict__ nw,
                       float* __restrict__ out_idx, int* __restrict__ counts,
                       int* __restrict__ tok_top, float* __restrict__ tok_w) {
    int t = blockIdx.x;
    int lane = threadIdx.x;                     // 64
    const float* xr = x + (size_t)t * Dc;
    double acc[Ec];
    #pragma unroll
    for (int e = 0; e < Ec; e++) acc[e] = 0.0;
    for (int i = 0; i < Dc/64; i++) {
        int d = lane + i*64;
        double xv = (double)xr[d];
        #pragma unroll
        for (int e = 0; e < Ec; e++) acc[e] += xv * (double)Wg[e*Dc + d];
    }
    #pragma unroll
    for (int e = 0; e < Ec; e++)
        for (int off = 32; off > 0; off >>= 1)
            acc[e] += __shfl_down(acc[e], off);
    if (lane == 0) {
        double noisy[Ec];
        #pragma unroll
        for (int e = 0; e < Ec; e++)
            noisy[e] = acc[e] + (double)noise[t*Ec + e] * (double)nw[e];
        int i0 = 0;
        for (int e = 1; e < Ec; e++) if (noisy[e] > noisy[i0]) i0 = e;   // ties -> lowest idx
        int i1 = -1;
        for (int e = 0; e < Ec; e++) {
            if (e == i0) continue;
            if (i1 < 0 || noisy[e] > noisy[i1]) i1 = e;
        }
        double ee = exp(noisy[i1] - noisy[i0]);   // v1 <= v0, stable
        float w0 = (float)(1.0 / (1.0 + ee));
        float w1 = (float)(ee / (1.0 + ee));
        out_idx[t*2 + 0] = (float)i0;
        out_idx[t*2 + 1] = (float)i1;
        tok_top[t*2] = i0; tok_top[t*2+1] = i1;
        tok_w[t*2] = w0;   tok_w[t*2+1] = w1;
        atomicAdd(&counts[i0], 1);
        atomicAdd(&counts[i1], 1);
    }
}

__global__ void k_scan(const int* __restrict__ counts, int* __restrict__ offsets) {
    if (threadIdx.x == 0) {
        int s = 0;
        for (int e = 0; e < Ec; e++) { offsets[e] = s; s += counts[e]; }
        offsets[Ec] = s;
    }
}

__global__ void k_fill(const int* __restrict__ tok_top, const int* __restrict__ offsets,
                       int* __restrict__ fill, int* __restrict__ slot_token,
                       int* __restrict__ slot_of, int* __restrict__ slot_pos) {
    int t = blockIdx.x * 256 + threadIdx.x;
    if (t >= Tc) return;
    #pragma unroll
    for (int j = 0; j < 2; j++) {
        int e = tok_top[t*2 + j];
        int pos = atomicAdd(&fill[e], 1);
        int slot = offsets[e] + pos;
        slot_token[slot] = t;
        slot_of[t*2 + j] = slot;
        slot_pos[slot] = pos;                 // expert-local row (swizzle key source)
    }
}

// ---- pack A: gather + cvt into K-panel-major APK[kp=32][SLOTPAD][32], pre-swizzled ----
__global__ void k_packA(const float* __restrict__ x, const int* __restrict__ slot_token,
                        const int* __restrict__ slot_pos, unsigned short* __restrict__ apk) {
    int s = blockIdx.x * 4 + (threadIdx.x >> 6);
    int lane = threadIdx.x & 63;
    int token = slot_token[s];
    int pos = slot_pos[s];
    const float4* px = (const float4*)(x + (size_t)token * Dc) + lane*4;
    float4 v0 = px[0], v1 = px[1], v2 = px[2], v3 = px[3];
    uint4 lo, hi;
    lo.x = pack2bf(v0.x, v0.y); lo.y = pack2bf(v0.z, v0.w);
    lo.z = pack2bf(v1.x, v1.y); lo.w = pack2bf(v1.z, v1.w);
    hi.x = pack2bf(v2.x, v2.y); hi.y = pack2bf(v2.z, v2.w);
    hi.z = pack2bf(v3.x, v3.y); hi.w = pack2bf(v3.z, v3.w);
    int kp = lane >> 1;
    int key = (pos >> 1) & 3;
    int c0 = (lane & 1) * 2;
    size_t base = (size_t)kp * PROWS + (size_t)s * 32;
    *(uint4*)&apk[base + ((c0 ^ key) * 8)]       = lo;
    *(uint4*)&apk[base + (((c0+1) ^ key) * 8)]   = hi;
}

// ---------------- GEMM1: HH = (X@W1+b1) * silu(X@W2+b2), per expert ----------------
// Best-measured cell (R9/R11/R15): default 3D grid (bx fastest -> 64 consecutive blocks
// share one A-tile), 128 slots x 64 hcols x both matrices; 4 waves, single 64x64
// acc/wave; 2-slot ring + counted vmcnt + raw barriers; 32KB LDS; 4 blocks/CU.
__global__ __launch_bounds__(256, 4) void k_gemm1(
    const unsigned short* __restrict__ apk,
    const unsigned short* __restrict__ w1p, const unsigned short* __restrict__ w2p,
    const float* __restrict__ b1, const float* __restrict__ b2,
    const int* __restrict__ counts, const int* __restrict__ offsets,
    unsigned short* __restrict__ hh2) {
    int e = blockIdx.z;
    int n_e = counts[e];
    int m0 = blockIdx.y * 128;
    if (m0 >= n_e) return;
    int base = offsets[e];
    int bx = blockIdx.x;                 // 64 x-blocks of 64 h-cols
    int n0 = bx * 64;
    int hp = bx >> 1, ro = (bx & 1) * 64;   // 128-panel + row offset inside it

    __shared__ __align__(16) unsigned char smem[32768];
    unsigned short* sU = (unsigned short*)smem;   // A slot s: +s*4096, B slot s: +8192+s*4096
    float* sS = (float*)smem;                     // [128][64] epilogue silu exchange (aliases)

    int tid = threadIdx.x;
    int wid = tid >> 6, lane = tid & 63;
    int wr = wid >> 1, wc = wid & 1;

    // contiguous staging sources
    const unsigned short* aSrc = apk + (size_t)(base + m0 + wid*32)*32 + lane*8;   // + kk*PROWS
    const unsigned short* wmat = (wid < 2) ? w1p : w2p;
    const unsigned short* bSrc = wmat + ((size_t)(e*32 + hp) * 32) * 4096
                               + (size_t)(ro + (wid & 1)*32)*32 + lane*8;          // + kk*4096

    int arow = lane & 15, cr = lane >> 4;
    int ccf = cr ^ ((arow >> 1) & 3);
    int aoff[4], boff[4];
    #pragma unroll
    for (int m = 0; m < 4; m++) aoff[m] = (wr*64 + m*16 + arow)*32 + ccf*8;
    #pragma unroll
    for (int n = 0; n < 4; n++) boff[n] = 8192 + (wc*64 + n*16 + arow)*32 + ccf*8;

    f32x4 acc[4][4];
    #pragma unroll
    for (int m = 0; m < 4; m++)
        #pragma unroll
        for (int n = 0; n < 4; n++)
            #pragma unroll
            for (int j = 0; j < 4; j++) acc[m][n][j] = 0.0f;

    // rolling stage pointers (no per-step 64-bit multiplies)
    const unsigned short* aStage = aSrc;
    const unsigned short* bStage = bSrc;

    auto STAGE = [&](int s) {   // stages the tile currently pointed at; 4 contiguous 1KB loads
        unsigned short* dA = sU + s*4096 + wid*1024;
        unsigned short* dB = sU + 8192 + s*4096 + wid*1024;
        gload16(aStage,       dA); gload16(aStage + 512, dA + 512);
        gload16(bStage,       dB); gload16(bStage + 512, dB + 512);
        aStage += PROWS; bStage += 4096;
    };

    const int NK = Dc / 32;   // 32
    STAGE(0); STAGE(1);
    for (int kk = 0; kk < NK; ++kk) {
        int s = kk & 1;
        const unsigned short* sl = sU + s*4096;
        if (kk < NK - 1) { asm volatile("s_waitcnt vmcnt(4)" ::: "memory"); }
        else             { asm volatile("s_waitcnt vmcnt(0)" ::: "memory"); }
        fence_bar();                          // slot s published to all waves
        bf16x8 af[4], bf[4];
        #pragma unroll
        for (int m = 0; m < 4; m++) af[m] = *(const bf16x8*)&sl[aoff[m]];
        #pragma unroll
        for (int n = 0; n < 4; n++) bf[n] = *(const bf16x8*)&sl[boff[n]];
        #pragma unroll
        for (int m = 0; m < 4; m++)
            #pragma unroll
            for (int n = 0; n < 4; n++)
                acc[m][n] = __builtin_amdgcn_mfma_f32_16x16x32_bf16(af[m], bf[n], acc[m][n], 0, 0, 0);
        fence_bar();                          // all waves done reading slot s (WAR license)
        if (kk + 2 < NK) STAGE(s);            // refill slot s; waited at iter kk+2
    }

    // epilogue: wc=1 publish silu(h2) to LDS; wc=0 multiply+store.
    // row-parity XOR on the column (function of row only, same on write and read).
    int lrow = (lane >> 4) * 4, lcol = lane & 15;
    if (wc == 1) {
        #pragma unroll
        for (int n = 0; n < 4; n++) {
            float b2v = b2[e*Hc + n0 + n*16 + lcol];
            #pragma unroll
            for (int m = 0; m < 4; m++) {
                int rb = wr*64 + m*16 + lrow;
                #pragma unroll
                for (int j = 0; j < 4; j++) {
                    int row = rb + j;
                    float h2 = acc[m][n][j] + b2v;
                    sS[row*64 + ((n*16 + lcol) ^ ((((row) >> 2) & 1) << 4))] = h2 / (1.0f + expf(-h2));
                }
            }
        }
    }
    __syncthreads();
    if (wc == 0) {
        #pragma unroll
        for (int n = 0; n < 4; n++) {
            int hcol = n0 + n*16 + lcol;
            float b1v = b1[e*Hc + hcol];
            int hp2 = hcol >> 5;
            int ch  = (hcol >> 3) & 3;
            int ho  = hcol & 7;
            #pragma unroll
            for (int m = 0; m < 4; m++) {
                int rb = wr*64 + m*16 + lrow;
                #pragma unroll
                for (int j = 0; j < 4; j++) {
                    int row = rb + j;
                    int r = m0 + row;
                    if (r < n_e) {
                        float sv = sS[row*64 + ((n*16 + lcol) ^ ((((row) >> 2) & 1) << 4))];
                        float v = (acc[m][n][j] + b1v) * sv;
                        int key = (r >> 1) & 3;
                        hh2[(size_t)hp2 * PROWS + (size_t)(base + r)*32 + ((ch ^ key)*8) + ho] = f2bf(v);
                    }
                }
            }
        }
    }
}

// ---------------- GEMM2: OUT = HH @ Wp^T (+bp), per expert, K-split x2 ----------------
// Round-11/15 proven version: 3-slot ring, vmcnt(8), 48KB LDS, 3 blocks/CU; XCD owns
// expert; dp fastest (8 consecutive blocks share one HH A-tile). Partials in disjoint
// OUTB halves via plain stores; kc=0 adds bias.
__global__ __launch_bounds__(256, 3) void k_gemm2(
    const unsigned short* __restrict__ hh2,
    const unsigned short* __restrict__ wpp,
    const float* __restrict__ bp,
    const int* __restrict__ counts, const int* __restrict__ offsets,
    float* __restrict__ outb) {
    int d = blockIdx.x;                          // 0..4095 dispatch index
    int L = (d & 7) * 512 + (d >> 3);            // bijective; XCD i owns L in [i*512,(i+1)*512)
    int dp = L & 7;                              // FASTEST (A-tile shared by 8 consecutive blocks)
    int yy = (L >> 3) & 63;
    int e  = L >> 9;                             // expert per XCD
    int n_e = counts[e];
    int kc = yy & 1;                             // K-chunk
    int m0 = (yy >> 1) * 128;
    if (m0 >= n_e) return;
    int base = offsets[e];
    int n0 = dp * 128;
    float* out = outb + (size_t)kc * NSLOT * Dc; // disjoint partial half

    __shared__ __align__(16) unsigned char smem[49152];
    unsigned short* sU = (unsigned short*)smem;  // slot s: A at +s*8192, B at +s*8192+4096

    int tid = threadIdx.x;
    int wid = tid >> 6, lane = tid & 63;
    int wr = wid >> 1, wc = wid & 1;

    const int k0 = kc * 64;                      // first 32-wide K-panel of this chunk
    const unsigned short* aSrc = hh2 + (size_t)k0*PROWS
                               + (size_t)(base + m0 + wid*32)*32 + lane*8;           // + kk*PROWS
    const unsigned short* bSrc = wpp + ((size_t)(e*8 + dp) * 128) * 4096
                               + (size_t)k0*4096 + wid*1024 + lane*8;                // + kk*4096

    int arow = lane & 15, cr = lane >> 4;
    int ccf = cr ^ ((arow >> 1) & 3);
    int aoff[4], boff[4];
    #pragma unroll
    for (int m = 0; m < 4; m++) aoff[m] = (wr*64 + m*16 + arow)*32 + ccf*8;
    #pragma unroll
    for (int n = 0; n < 4; n++) boff[n] = 4096 + (wc*64 + n*16 + arow)*32 + ccf*8;

    f32x4 acc[4][4];
    #pragma unroll
    for (int m = 0; m < 4; m++)
        #pragma unroll
        for (int n = 0; n < 4; n++)
            #pragma unroll
            for (int j = 0; j < 4; j++) acc[m][n][j] = 0.0f;

    const unsigned short* aStage = aSrc;
    const unsigned short* bStage = bSrc;
    auto STAGE = [&](int s) {
        unsigned short* dA = sU + s*8192 + wid*1024;
        unsigned short* dB = sU + s*8192 + 4096 + wid*1024;
        gload16(aStage,       dA); gload16(aStage + 512, dA + 512);
        gload16(bStage,       dB); gload16(bStage + 512, dB + 512);
        aStage += PROWS; bStage += 4096;
    };

    const int NK = 64;                   // 2048 K per chunk / 32
    STAGE(0); STAGE(1); STAGE(2);        // tiles 0,1,2 in flight (12 loads/wave)
    int s = 0;
    for (int kk = 0; kk < NK; ++kk) {
        const unsigned short* sl = sU + s*8192;
        if (kk + 3 <= NK - 1)      { asm volatile("s_waitcnt vmcnt(8)" ::: "memory"); }
        else if (kk + 2 <= NK - 1) { asm volatile("s_waitcnt vmcnt(4)" ::: "memory"); }
        else                       { asm volatile("s_waitcnt vmcnt(0)" ::: "memory"); }
        fence_bar();                          // tile kk published
        bf16x8 af[4], bf[4];
        #pragma unroll
        for (int m = 0; m < 4; m++) af[m] = *(const bf16x8*)&sl[aoff[m]];
        #pragma unroll
        for (int n = 0; n < 4; n++) bf[n] = *(const bf16x8*)&sl[boff[n]];
        #pragma unroll
        for (int m = 0; m < 4; m++)
            #pragma unroll
            for (int n = 0; n < 4; n++)
                acc[m][n] = __builtin_amdgcn_mfma_f32_16x16x32_bf16(af[m], bf[n], acc[m][n], 0, 0, 0);
        fence_bar();                          // WAR license on slot s
        if (kk + 3 < NK) STAGE(s);            // stage tile kk+3 into freed slot
        s = (s == 2) ? 0 : s + 1;
    }

    int lrow = (lane >> 4) * 4, lcol = lane & 15;
    #pragma unroll
    for (int n = 0; n < 4; n++) {
        int dcol = n0 + wc*64 + n*16 + lcol;
        float badd = (kc == 0) ? bp[e*Dc + dcol] : 0.0f;
        #pragma unroll
        for (int m = 0; m < 4; m++) {
            int rb2 = m0 + wr*64 + m*16 + lrow;
            #pragma unroll
            for (int j = 0; j < 4; j++) {
                int r = rb2 + j;
                if (r < n_e)
                    out[(size_t)(base + r)*Dc + dcol] = acc[m][n][j] + badd;
            }
        }
    }
}

// ---------------- combine: final[t] = w0*(P0+P1)[s0] + w1*(P0+P1)[s1] ----------------
__global__ void k_combine(const float* __restrict__ outb, const int* __restrict__ slot_of,
                          const float* __restrict__ tok_w, float* __restrict__ final_out) {
    int gid = blockIdx.x * 256 + threadIdx.x;   // Tc*Dc/4 threads
    int t = gid >> 8;
    int c = (gid & 255) * 4;
    int s0 = slot_of[t*2], s1 = slot_of[t*2 + 1];
    float w0 = tok_w[t*2], w1 = tok_w[t*2 + 1];
    const float* p1 = outb + (size_t)NSLOT * Dc;
    float4 a0 = *(const float4*)&outb[(size_t)s0*Dc + c];
    float4 b0 = *(const float4*)&p1  [(size_t)s0*Dc + c];
    float4 a1 = *(const float4*)&outb[(size_t)s1*Dc + c];
    float4 b1v = *(const float4*)&p1 [(size_t)s1*Dc + c];
    float4 r;
    r.x = w0*(a0.x + b0.x) + w1*(a1.x + b1v.x);
    r.y = w0*(a0.y + b0.y) + w1*(a1.y + b1v.y);
    r.z = w0*(a0.z + b0.z) + w1*(a1.z + b1v.z);
    r.w = w0*(a0.w + b0.w) + w1*(a1.w + b1v.w);
    *(float4*)&final_out[(size_t)t*Dc + c] = r;
}

extern "C" void kernel_launch(void* const* d_in, const int* in_sizes, int n_in,
                              void* d_out, int out_size, void* d_ws, size_t ws_size,
                              hipStream_t stream) {
    (void)in_sizes; (void)n_in; (void)out_size; (void)ws_size;
    const float* x     = (const float*)d_in[0];
    const float* noise = (const float*)d_in[1];
    const float* Wg    = (const float*)d_in[2];
    const float* nw    = (const float*)d_in[3];
    const float* W1    = (const float*)d_in[4];
    const float* b1    = (const float*)d_in[5];
    const float* W2    = (const float*)d_in[6];
    const float* b2    = (const float*)d_in[7];
    const float* Wp    = (const float*)d_in[8];
    const float* bp    = (const float*)d_in[9];

    char* ws = (char*)d_ws;
    size_t off = 0;
    unsigned short* W1P = (unsigned short*)(ws + off); off += (size_t)Ec*Dc*Hc*2;      // 64 MB
    unsigned short* W2P = (unsigned short*)(ws + off); off += (size_t)Ec*Dc*Hc*2;      // 64 MB
    unsigned short* WPP = (unsigned short*)(ws + off); off += (size_t)Ec*Hc*Dc*2;      // 64 MB
    unsigned short* APK = (unsigned short*)(ws + off); off += (size_t)32*PROWS*2;      // 16.5 MB
    unsigned short* HH2 = (unsigned short*)(ws + off); off += (size_t)128*PROWS*2;     // 66 MB
    float*          OUTB= (float*)(ws + off);          off += (size_t)NSLOT*Dc*4*2;    // 64 MB (2 partials)
    int*   counts    = (int*)(ws + off);
    int*   fill      = (int*)(ws + off + 32);
    int*   offsets   = (int*)(ws + off + 64);
    int*   tok_top   = (int*)(ws + off + 128);
    float* tok_w     = (float*)(ws + off + 128 + (size_t)Tc*2*4);
    int*   slot_token= (int*)(ws + off + 128 + (size_t)Tc*2*8);
    int*   slot_of   = (int*)(ws + off + 128 + (size_t)Tc*2*8 + (size_t)NSLOT*4);
    int*   slot_pos  = (int*)(ws + off + 128 + (size_t)Tc*2*8 + (size_t)NSLOT*8);

    float* final_out = (float*)d_out;
    float* idx_out   = (float*)d_out + FINAL_N;

    (void)hipMemsetAsync(counts, 0, 64, stream);   // counts + fill

    // W1 + W2 panel transposes in one launch (z = 16: [0,8) -> W1, [8,16) -> W2)
    k_transpose_panel<<<dim3(Hc/64, Dc/64, 2*Ec), 256, 0, stream>>>(W1, W2, W1P, W2P, Dc, Hc, Ec);
    k_transpose_panel<<<dim3(Dc/64, Hc/64, Ec), 256, 0, stream>>>(Wp, Wp, WPP, WPP, Hc, Dc, Ec);

    k_gate<<<Tc, 64, 0, stream>>>(x, noise, Wg, nw, idx_out, counts, tok_top, tok_w);
    k_scan<<<1, 64, 0, stream>>>(counts, offsets);
    k_fill<<<Tc/256, 256, 0, stream>>>(tok_top, offsets, fill, slot_token, slot_of, slot_pos);
    k_packA<<<NSLOT/4, 256, 0, stream>>>(x, slot_token, slot_pos, APK);

    k_gemm1<<<dim3(Hc/64, Tc/128, Ec), 256, 0, stream>>>(APK, W1P, W2P, b1, b2,
                                                         counts, offsets, HH2);
    k_gemm2<<<4096, 256, 0, stream>>>(HH2, WPP, bp, counts, offsets, OUTB);
    k_combine<<<(Tc*Dc/4)/256, 256, 0, stream>>>(OUTB, slot_of, tok_w, final_out);
}